// Round 3
// baseline (3613.428 us; speedup 1.0000x reference)
//
#include <hip/hip_runtime.h>

// NLReader bidirectional LSTM, MI355X — single persistent scan kernel.
// ALL float tensors are float32 (per the reference); data is int32.
// MFMA runs on bf16-converted operands with f32 accumulation; c-state is f32
// in registers for all 128 steps; h is double-buffered bf16 in ws (internal).
//
//   128 blocks x 256 thr, plain launch (co-resident on 256 CUs).
//   Block (dir = bid>>6, kb = bid&63) owns 8 hidden units = 32 permuted gate
//   columns p = jj*4+g (orig = g*512 + kb*8 + jj) -> gates i/f/g/o of one unit
//   land in 4 adjacent lanes => 3 shfl_xor replace any cross-block exchange.
//   Whh/Wih B-fragments live in registers (step-invariant, ~256 VGPR).
//   x-projection (emb @ Wih^T) is computed BEFORE the inter-block barrier each
//   step (depends only on inputs) -> hidden behind the barrier wait.
//   Cross-block sync: per-wave monotone flags (producer: threadfence + relaxed
//   agent store s+1; consumer: 64 lanes poll 4 flags each, then threadfence).
// ws footprint: 256 KB h + 2 KB flags + 2 KB zero-row = 260 KB.

typedef float  f32x4  __attribute__((ext_vector_type(4)));
typedef __bf16 bf16x8 __attribute__((ext_vector_type(8)));
typedef __bf16 bf16;

#define HB_OFF   ((size_t)0)        // 4 x [64 x 512] bf16 = 262144 B
#define FLAG_OFF ((size_t)262144)   // 512 x u32 = 2048 B
#define ZROW_OFF ((size_t)264192)   // 512 f32 zero embedding row = 2048 B
#define WS_ZERO_BYTES ((size_t)266240)

__device__ __forceinline__ float sigmoidf_(float x) {
    return 1.0f / (1.0f + __expf(-x));
}
__device__ __forceinline__ float tanhf_(float x) {
    return 2.0f * sigmoidf_(2.0f * x) - 1.0f;
}
__device__ __forceinline__ bf16x8 load_cvt8(const float* p) {
    float4 a = *(const float4*)p;
    float4 b = *(const float4*)(p + 4);
    bf16x8 r;
    r[0] = (bf16)a.x; r[1] = (bf16)a.y; r[2] = (bf16)a.z; r[3] = (bf16)a.w;
    r[4] = (bf16)b.x; r[5] = (bf16)b.y; r[6] = (bf16)b.z; r[7] = (bf16)b.w;
    return r;
}

__global__ __launch_bounds__(256) void init_ws(unsigned long long* __restrict__ w) {
    const size_t i = (size_t)blockIdx.x * 256 + threadIdx.x;
    if (i < WS_ZERO_BYTES / 8) w[i] = 0ull;
}

__global__ __launch_bounds__(256, 1) void lstm_scan(
    const int*   __restrict__ data,    // [128,64] int32, -1 = pad
    const float* __restrict__ mask,    // [128,64] f32 (0/1)
    const float* __restrict__ table,   // [32001,512] f32
    const float* __restrict__ wih_f, const float* __restrict__ whh_f,
    const float* __restrict__ bih_f, const float* __restrict__ bhh_f,
    const float* __restrict__ wih_b, const float* __restrict__ whh_b,
    const float* __restrict__ bih_b, const float* __restrict__ bhh_b,
    bf16* __restrict__ hbuf,           // [dir][buf][64][512] bf16 (internal)
    unsigned* __restrict__ flags,      // 512 per-wave monotone flags
    const float* __restrict__ zrow,    // 512 zeros
    float* __restrict__ out)           // [128,64,1024] f32
{
    __shared__ float sM[128 * 64];     // full mask, 32 KB
    __shared__ int   sData[128 * 64];  // full token ids, 32 KB

    const int tid = threadIdx.x, bid = blockIdx.x;
    const int dir = bid >> 6, kb = bid & 63;
    const int wave = tid >> 6, lane = tid & 63;
    const int c = lane & 15, q = lane >> 4, g = c & 3;

    const float* wih = dir ? wih_b : wih_f;
    const float* whh = dir ? whh_b : whh_f;
    const float* bih = dir ? bih_b : bih_f;
    const float* bhh = dir ? bhh_b : bhh_f;

    for (int i = tid; i < 2048; i += 256)
        *(uint4*)(&sM[i * 4]) = *(const uint4*)(&mask[i * 4]);
    for (int i = tid; i < 2048; i += 256)
        *(uint4*)(&sData[i * 4]) = *(const uint4*)(&data[i * 4]);

    // Step-invariant B-fragments in registers (f32 -> bf16 once).
    // n = t4*16 + c is the local permuted col; orig = (n&3)*512 + kb*8 + (n>>2).
    // B-frag layout (16x16x32): lane holds B[k = q*8 + j][n = c].
    bf16x8 Wr[32], Vr[32];
    float bias_v[2];
#pragma unroll
    for (int t4 = 0; t4 < 2; ++t4) {
        const int n = t4 * 16 + c;
        const size_t orig = (size_t)((n & 3) * 512 + kb * 8 + (n >> 2));
#pragma unroll
        for (int kc = 0; kc < 16; ++kc) {
            Wr[kc * 2 + t4] = load_cvt8(&whh[orig * 512 + kc * 32 + q * 8]);
            Vr[kc * 2 + t4] = load_cvt8(&wih[orig * 512 + kc * 32 + q * 8]);
        }
        bias_v[t4] = bih[orig] + bhh[orig];
    }

    float cst[2][4] = {{0.f, 0.f, 0.f, 0.f}, {0.f, 0.f, 0.f, 0.f}};
    const int hrow = 16 * wave + c;        // A-fragment row (batch index)
    const int myflag = dir * 256 + kb * 4 + wave;
    const int fbase = dir * 256;
    const f32x4 zz = {0.f, 0.f, 0.f, 0.f};
    __syncthreads();                        // sM/sData ready; no syncs after this

    for (int s = 0; s < 128; ++s) {
        const int tt = dir ? (127 - s) : s;

        // ---- x-projection: independent of h, overlaps stragglers of step s-1
        const int qv = sData[tt * 64 + hrow];
        const float* erow = (qv >= 0) ? (table + (size_t)qv * 512) : zrow;
        f32x4 accx0 = zz, accx1 = zz;
#pragma unroll
        for (int kc = 0; kc < 16; ++kc) {
            const bf16x8 e = load_cvt8(erow + kc * 32 + q * 8);
            accx0 = __builtin_amdgcn_mfma_f32_16x16x32_bf16(e, Vr[kc * 2 + 0], accx0, 0, 0, 0);
            accx1 = __builtin_amdgcn_mfma_f32_16x16x32_bf16(e, Vr[kc * 2 + 1], accx1, 0, 0, 0);
        }

        // ---- wait for all 256 producer waves of this dir to reach level s ----
        const unsigned tgt = (unsigned)s;   // flag f => that wave completed f steps
        for (;;) {
            const unsigned a0 = __hip_atomic_load(flags + fbase + lane,       __ATOMIC_RELAXED, __HIP_MEMORY_SCOPE_AGENT);
            const unsigned a1 = __hip_atomic_load(flags + fbase + 64  + lane, __ATOMIC_RELAXED, __HIP_MEMORY_SCOPE_AGENT);
            const unsigned a2 = __hip_atomic_load(flags + fbase + 128 + lane, __ATOMIC_RELAXED, __HIP_MEMORY_SCOPE_AGENT);
            const unsigned a3 = __hip_atomic_load(flags + fbase + 192 + lane, __ATOMIC_RELAXED, __HIP_MEMORY_SCOPE_AGENT);
            if (__all(a0 >= tgt && a1 >= tgt && a2 >= tgt && a3 >= tgt)) break;
            __builtin_amdgcn_s_sleep(1);
        }
        __threadfence();                    // acquire: h of step s-1 visible

        const bf16* hb = hbuf + (size_t)(dir * 2 + (s & 1)) * (64 * 512);
        bf16*       hw = hbuf + (size_t)(dir * 2 + ((s + 1) & 1)) * (64 * 512);

        // ---- h-projection: A-frag lane holds h[b = hrow][k = kc*32 + q*8 + j]
        uint4 af[16];
#pragma unroll
        for (int kc = 0; kc < 16; ++kc)
            af[kc] = *(const uint4*)(&hb[hrow * 512 + kc * 32 + q * 8]);

        f32x4 acc0 = zz, acc1 = zz;
#pragma unroll
        for (int kc = 0; kc < 16; ++kc) {
            const bf16x8 a = __builtin_bit_cast(bf16x8, af[kc]);
            acc0 = __builtin_amdgcn_mfma_f32_16x16x32_bf16(a, Wr[kc * 2 + 0], acc0, 0, 0, 0);
            acc1 = __builtin_amdgcn_mfma_f32_16x16x32_bf16(a, Wr[kc * 2 + 1], acc1, 0, 0, 0);
        }

        // ---- epilogue: gates -> (h,c); C/D layout col=lane&15, row=q*4+r ----
        float hreg[2][4];
#pragma unroll
        for (int t4 = 0; t4 < 2; ++t4) {
            const f32x4 A  = t4 ? acc1  : acc0;
            const f32x4 AX = t4 ? accx1 : accx0;
#pragma unroll
            for (int r = 0; r < 4; ++r) {
                const int b_ = 16 * wave + 4 * q + r;
                float v = A[r] + AX[r] + bias_v[t4];
                // quad lanes {4j..4j+3} hold gates i,f,g,o of one unit
                const float v1 = __shfl_xor(v, 1);
                const float v2 = __shfl_xor(v, 2);
                const float v3 = __shfl_xor(v, 3);
                const float gi = (g == 0) ? v  : (g == 1) ? v1 : (g == 2) ? v2 : v3;
                const float gf = (g == 0) ? v1 : (g == 1) ? v  : (g == 2) ? v3 : v2;
                const float gG = (g == 0) ? v2 : (g == 1) ? v3 : (g == 2) ? v  : v1;
                const float go = (g == 0) ? v3 : (g == 1) ? v2 : (g == 2) ? v1 : v;
                const float is_ = sigmoidf_(gi);
                const float fs_ = sigmoidf_(gf);
                const float gt_ = tanhf_(gG);
                const float os_ = sigmoidf_(go);
                const float cn  = fs_ * cst[t4][r] + is_ * gt_;
                float hv        = os_ * tanhf_(cn);
                const float m   = sM[tt * 64 + b_];
                cst[t4][r] = cn * m;        // f32 c-state never leaves registers
                hv *= m;
                hreg[t4][r] = hv;
                if (g == 0)                  // one lane per unit writes h (bf16)
                    hw[b_ * 512 + kb * 8 + t4 * 4 + (c >> 2)] = (bf16)hv;
            }
        }

        __threadfence();                     // release h-writes (L2 wb for agent)
        if (lane == 0)
            __hip_atomic_store(flags + myflag, (unsigned)(s + 1),
                               __ATOMIC_RELAXED, __HIP_MEMORY_SCOPE_AGENT);

        // out-writes (f32) are off the recurrence critical path: after the flag
#pragma unroll
        for (int t4 = 0; t4 < 2; ++t4)
#pragma unroll
            for (int r = 0; r < 4; ++r)
                if (g == 0) {
                    const int b_ = 16 * wave + 4 * q + r;
                    out[(size_t)(tt * 64 + b_) * 1024 + dir * 512 + kb * 8 + t4 * 4 + (c >> 2)]
                        = hreg[t4][r];
                }
    }
}

extern "C" void kernel_launch(void* const* d_in, const int* in_sizes, int n_in,
                              void* d_out, int out_size, void* d_ws, size_t ws_size,
                              hipStream_t stream) {
    const int*   data  = (const int*)d_in[0];
    const float* mask  = (const float*)d_in[1];
    const float* table = (const float*)d_in[2];
    const float* wih_f = (const float*)d_in[3];
    const float* whh_f = (const float*)d_in[4];
    const float* bih_f = (const float*)d_in[5];
    const float* bhh_f = (const float*)d_in[6];
    const float* wih_b = (const float*)d_in[7];
    const float* whh_b = (const float*)d_in[8];
    const float* bih_b = (const float*)d_in[9];
    const float* bhh_b = (const float*)d_in[10];
    float* outp = (float*)d_out;

    char* ws = (char*)d_ws;
    bf16*       hbuf  = (bf16*)(ws + HB_OFF);
    unsigned*   flagp = (unsigned*)(ws + FLAG_OFF);
    const float* zrow = (const float*)(ws + ZROW_OFF);

    init_ws<<<(int)((WS_ZERO_BYTES / 8 + 255) / 256), 256, 0, stream>>>(
        (unsigned long long*)ws);
    lstm_scan<<<128, 256, 0, stream>>>(data, mask, table,
                                       wih_f, whh_f, bih_f, bhh_f,
                                       wih_b, whh_b, bih_b, bhh_b,
                                       hbuf, flagp, zrow, outp);
}

// Round 4
// 1723.836 us; speedup vs baseline: 2.0962x; 2.0962x over previous
//
#include <hip/hip_runtime.h>

// NLReader bidirectional LSTM, MI355X — persistent scan, fence-free relay.
// All cross-block traffic (h, flags) uses RELAXED agent-scope atomics (sc0 sc1
// -> straight to MALL coherence point). No __threadfence in the loop -> no
// buffer_wbl2 / buffer_inv full-cache maintenance per step (round-3 killer).
// Release: s_waitcnt vmcnt(0) between h-stores and flag store (all prior
// cross-visible stores are sc1 atomics). Acquire: control dep + compiler
// barrier; sc1 loads can't be stale.
//
// Block (dir=bid>>6, kb=bid&63) owns 8 hidden units as 32 permuted gate cols:
//   tile t4 in {0,1}, lane col c in [0,16): gate g = c&3, unit jj = 2*(c>>2)+t4
//   orig Wih/Whh row = g*512 + kb*8 + jj.
// Gates i/f/g/o of one unit sit in a lane quad (shfl_xor 1/2/3 exchange);
// t4=0/1 give ADJACENT units -> one packed u32 (2xbf16) h-store per lane.
// Weights live in LDS as pre-swizzled bf16 fragments (32KB Whh + 32KB Wih).
// c-state stays f32 in registers for all 128 steps; h bf16 double-buffered.

typedef float  f32x4  __attribute__((ext_vector_type(4)));
typedef __bf16 bf16x8 __attribute__((ext_vector_type(8)));
typedef __bf16 bf16;

#define HB_OFF   ((size_t)0)        // 4 x [64 x 512] bf16 = 262144 B
#define FLAG_OFF ((size_t)262144)   // 512 x u32 = 2048 B
#define ZROW_OFF ((size_t)264192)   // 512 f32 zero embedding row = 2048 B
#define WS_ZERO_BYTES ((size_t)266240)

__device__ __forceinline__ float sigmoidf_(float x) {
    return 1.0f / (1.0f + __expf(-x));
}
__device__ __forceinline__ float tanhf_(float x) {
    return 2.0f * sigmoidf_(2.0f * x) - 1.0f;
}
__device__ __forceinline__ bf16x8 cvt8(const float* p) {
    float4 a = *(const float4*)p;
    float4 b = *(const float4*)(p + 4);
    bf16x8 r;
    r[0] = (bf16)a.x; r[1] = (bf16)a.y; r[2] = (bf16)a.z; r[3] = (bf16)a.w;
    r[4] = (bf16)b.x; r[5] = (bf16)b.y; r[6] = (bf16)b.z; r[7] = (bf16)b.w;
    return r;
}

__global__ __launch_bounds__(256) void init_ws(unsigned long long* __restrict__ w) {
    const size_t i = (size_t)blockIdx.x * 256 + threadIdx.x;
    if (i < WS_ZERO_BYTES / 8) w[i] = 0ull;
}

__global__ __launch_bounds__(256, 1) void lstm_scan(
    const int*   __restrict__ data,    // [128,64] int32, -1 = pad
    const float* __restrict__ mask,    // [128,64] f32 (0/1)
    const float* __restrict__ table,   // [32001,512] f32
    const float* __restrict__ wih_f, const float* __restrict__ whh_f,
    const float* __restrict__ bih_f, const float* __restrict__ bhh_f,
    const float* __restrict__ wih_b, const float* __restrict__ whh_b,
    const float* __restrict__ bih_b, const float* __restrict__ bhh_b,
    bf16* __restrict__ hbuf,           // [dir][buf][64][512] bf16 (internal)
    unsigned* __restrict__ flags,      // 512 per-wave monotone flags
    const float* __restrict__ zrow,    // 512 zeros
    float* __restrict__ out)           // [128,64,1024] f32
{
    // Pre-swizzled weight fragments: entry e = kc*128 + t4*64 + q*16 + c
    // holds B[k = kc*32 + q*8 + j][permuted col (t4,c)] for j=0..7 (16 B).
    __shared__ bf16 sW[2048 * 8];      // Whh fragments, 32 KB
    __shared__ bf16 sV[2048 * 8];      // Wih fragments, 32 KB  (total 64 KB)

    const int tid = threadIdx.x, bid = blockIdx.x;
    const int dir = bid >> 6, kb = bid & 63;
    const int wave = tid >> 6, lane = tid & 63;
    const int c = lane & 15, q = lane >> 4, g = c & 3;

    const float* wih = dir ? wih_b : wih_f;
    const float* whh = dir ? whh_b : whh_f;
    const float* bih = dir ? bih_b : bih_f;
    const float* bhh = dir ? bhh_b : bhh_f;

    // stage weight fragments (f32 -> bf16, swizzled)
    for (int e = tid; e < 2048; e += 256) {
        const int ec = e & 15, eq = (e >> 4) & 3, et = (e >> 6) & 1, ekc = e >> 7;
        const size_t orig = (size_t)((ec & 3) * 512 + kb * 8 + 2 * (ec >> 2) + et);
        const size_t off = orig * 512 + ekc * 32 + eq * 8;
        *(bf16x8*)(&sW[e * 8]) = cvt8(&whh[off]);
        *(bf16x8*)(&sV[e * 8]) = cvt8(&wih[off]);
    }
    float bias_v[2];
#pragma unroll
    for (int t4 = 0; t4 < 2; ++t4) {
        const int orig = g * 512 + kb * 8 + 2 * (c >> 2) + t4;
        bias_v[t4] = bih[orig] + bhh[orig];
    }

    float cst[2][4] = {{0.f, 0.f, 0.f, 0.f}, {0.f, 0.f, 0.f, 0.f}};
    const int hrow = 16 * wave + c;        // A-fragment row (batch index)
    const int myflag = dir * 256 + kb * 4 + wave;
    const int fbase = dir * 256;
    const f32x4 zz = {0.f, 0.f, 0.f, 0.f};
    __syncthreads();                        // sW/sV ready; no syncs after this

    for (int s = 0; s < 128; ++s) {
        const int tt = dir ? (127 - s) : s;

        // ---- x-projection (independent of h; overlaps stragglers of s-1) ----
        const int qv = data[tt * 64 + hrow];               // L2-hot
        const float* erow = (qv >= 0) ? (table + (size_t)qv * 512) : zrow;
        const float4 mv = *(const float4*)(&mask[tt * 64 + 16 * wave + 4 * q]);
        f32x4 accx0 = zz, accx1 = zz;
#pragma unroll
        for (int kc = 0; kc < 16; ++kc) {
            const bf16x8 e = cvt8(erow + kc * 32 + q * 8);
            const bf16x8 b0 = *(const bf16x8*)(&sV[(kc * 128 + q * 16 + c) * 8]);
            const bf16x8 b1 = *(const bf16x8*)(&sV[(kc * 128 + 64 + q * 16 + c) * 8]);
            accx0 = __builtin_amdgcn_mfma_f32_16x16x32_bf16(e, b0, accx0, 0, 0, 0);
            accx1 = __builtin_amdgcn_mfma_f32_16x16x32_bf16(e, b1, accx1, 0, 0, 0);
        }

        // ---- wait: all 256 waves of this dir completed step s-1 ----
        const unsigned tgt = (unsigned)s;
        for (;;) {
            const unsigned a0 = __hip_atomic_load(flags + fbase + lane,       __ATOMIC_RELAXED, __HIP_MEMORY_SCOPE_AGENT);
            const unsigned a1 = __hip_atomic_load(flags + fbase + 64  + lane, __ATOMIC_RELAXED, __HIP_MEMORY_SCOPE_AGENT);
            const unsigned a2 = __hip_atomic_load(flags + fbase + 128 + lane, __ATOMIC_RELAXED, __HIP_MEMORY_SCOPE_AGENT);
            const unsigned a3 = __hip_atomic_load(flags + fbase + 192 + lane, __ATOMIC_RELAXED, __HIP_MEMORY_SCOPE_AGENT);
            if (__all(a0 >= tgt && a1 >= tgt && a2 >= tgt && a3 >= tgt)) break;
            __builtin_amdgcn_s_sleep(1);
        }
        __asm__ volatile("" ::: "memory");   // keep h-loads below the poll

        const bf16* hb = hbuf + (size_t)(dir * 2 + (s & 1)) * (64 * 512);
        bf16*       hw = hbuf + (size_t)(dir * 2 + ((s + 1) & 1)) * (64 * 512);

        // ---- h A-fragments via relaxed agent atomic u64 loads (sc1, MALL) ----
        const unsigned long long* hq = (const unsigned long long*)hb;
        uint4 af[16];
#pragma unroll
        for (int kc = 0; kc < 16; ++kc) {
            const int i0 = hrow * 128 + kc * 8 + q * 2;
            ulonglong2 p;
            p.x = __hip_atomic_load(hq + i0,     __ATOMIC_RELAXED, __HIP_MEMORY_SCOPE_AGENT);
            p.y = __hip_atomic_load(hq + i0 + 1, __ATOMIC_RELAXED, __HIP_MEMORY_SCOPE_AGENT);
            af[kc] = __builtin_bit_cast(uint4, p);
        }

        f32x4 acc0 = zz, acc1 = zz;
#pragma unroll
        for (int kc = 0; kc < 16; ++kc) {
            const bf16x8 a  = __builtin_bit_cast(bf16x8, af[kc]);
            const bf16x8 b0 = *(const bf16x8*)(&sW[(kc * 128 + q * 16 + c) * 8]);
            const bf16x8 b1 = *(const bf16x8*)(&sW[(kc * 128 + 64 + q * 16 + c) * 8]);
            acc0 = __builtin_amdgcn_mfma_f32_16x16x32_bf16(a, b0, acc0, 0, 0, 0);
            acc1 = __builtin_amdgcn_mfma_f32_16x16x32_bf16(a, b1, acc1, 0, 0, 0);
        }

        // ---- epilogue: C/D layout col=lane&15, row=q*4+r ----
        unsigned* hw32 = (unsigned*)hw;
        float hreg[4][2];
#pragma unroll
        for (int r = 0; r < 4; ++r) {
            const int b_ = 16 * wave + 4 * q + r;
            const float m = (&mv.x)[r];
            float hv01[2];
#pragma unroll
            for (int t4 = 0; t4 < 2; ++t4) {
                float v = (t4 ? acc1[r] : acc0[r]) + (t4 ? accx1[r] : accx0[r]) + bias_v[t4];
                const float v1 = __shfl_xor(v, 1);
                const float v2 = __shfl_xor(v, 2);
                const float v3 = __shfl_xor(v, 3);
                const float gi = (g == 0) ? v  : (g == 1) ? v1 : (g == 2) ? v2 : v3;
                const float gf = (g == 0) ? v1 : (g == 1) ? v  : (g == 2) ? v3 : v2;
                const float gG = (g == 0) ? v2 : (g == 1) ? v3 : (g == 2) ? v  : v1;
                const float go = (g == 0) ? v3 : (g == 1) ? v2 : (g == 2) ? v1 : v;
                const float cn = sigmoidf_(gf) * cst[t4][r] + sigmoidf_(gi) * tanhf_(gG);
                float hv       = sigmoidf_(go) * tanhf_(cn);
                cst[t4][r] = cn * m;       // f32 c-state never leaves registers
                hv *= m;
                hv01[t4] = hv;
            }
            hreg[r][0] = hv01[0]; hreg[r][1] = hv01[1];
            if (g == 0) {                   // packed 2xbf16 -> one u32 sc1 store
                const unsigned u =
                    (unsigned)__builtin_bit_cast(unsigned short, (bf16)hv01[0]) |
                    ((unsigned)__builtin_bit_cast(unsigned short, (bf16)hv01[1]) << 16);
                __hip_atomic_store(hw32 + b_ * 256 + kb * 4 + (c >> 2), u,
                                   __ATOMIC_RELAXED, __HIP_MEMORY_SCOPE_AGENT);
            }
        }

        // release: all h sc1-stores at MALL before flag store (vmcnt(0) only)
        __asm__ volatile("" ::: "memory");
        __builtin_amdgcn_s_waitcnt(0x0F70);
        if (lane == 0)
            __hip_atomic_store(flags + myflag, (unsigned)(s + 1),
                               __ATOMIC_RELAXED, __HIP_MEMORY_SCOPE_AGENT);

        // out-writes (plain f32, off the relay critical path)
        if (g == 0) {
            const int j2 = dir * 512 + kb * 8 + 2 * (c >> 2);
#pragma unroll
            for (int r = 0; r < 4; ++r) {
                const int b_ = 16 * wave + 4 * q + r;
                float2 o2; o2.x = hreg[r][0]; o2.y = hreg[r][1];
                *(float2*)(&out[(size_t)(tt * 64 + b_) * 1024 + j2]) = o2;
            }
        }
    }
}

extern "C" void kernel_launch(void* const* d_in, const int* in_sizes, int n_in,
                              void* d_out, int out_size, void* d_ws, size_t ws_size,
                              hipStream_t stream) {
    const int*   data  = (const int*)d_in[0];
    const float* mask  = (const float*)d_in[1];
    const float* table = (const float*)d_in[2];
    const float* wih_f = (const float*)d_in[3];
    const float* whh_f = (const float*)d_in[4];
    const float* bih_f = (const float*)d_in[5];
    const float* bhh_f = (const float*)d_in[6];
    const float* wih_b = (const float*)d_in[7];
    const float* whh_b = (const float*)d_in[8];
    const float* bih_b = (const float*)d_in[9];
    const float* bhh_b = (const float*)d_in[10];
    float* outp = (float*)d_out;

    char* ws = (char*)d_ws;
    bf16*       hbuf  = (bf16*)(ws + HB_OFF);
    unsigned*   flagp = (unsigned*)(ws + FLAG_OFF);
    const float* zrow = (const float*)(ws + ZROW_OFF);

    init_ws<<<(int)((WS_ZERO_BYTES / 8 + 255) / 256), 256, 0, stream>>>(
        (unsigned long long*)ws);
    lstm_scan<<<128, 256, 0, stream>>>(data, mask, table,
                                       wih_f, whh_f, bih_f, bhh_f,
                                       wih_b, whh_b, bih_b, bhh_b,
                                       hbuf, flagp, zrow, outp);
}

// Round 8
// 1569.957 us; speedup vs baseline: 2.3016x; 1.0980x over previous
//
#include <hip/hip_runtime.h>

// NLReader bidirectional LSTM, MI355X — persistent scan, fence-free relay.
//
// Round-8: identical to round 7 except the batched-h asm outputs are
// EARLY-CLOBBER ("=&v"). Round 7's plain "=v" let the register allocator
// overlap an output with the 64-bit address input %16 -> the first load
// clobbered the address, subsequent loads dereferenced garbage -> device
// memory fault (core dump). "&" forces disjoint allocation.
//
// Structure: 128 blocks x 256 thr. All cross-block traffic via agent-scope
// (sc1, MALL coherence point) accesses; no __threadfence anywhere in the loop
// (no L2 writeback/invalidate storms — the round-3 killer). h-fetch is ONE
// asm node: 16x global_load_dwordx4 sc1 + s_waitcnt vmcnt(0), so exactly one
// MALL round trip per step (round-4 killer was ~10 serialized trips).
// x-projection software-pipelined one step ahead in the step tail (after the
// flag post) — off the relay critical path. W-fragments from LDS (pre-
// swizzled bf16). c-state f32 in registers all 128 steps; h bf16 dbuf in ws.
//
// Block (dir=bid>>6, kb=bid&63) owns 8 hidden units as 32 permuted gate cols:
//   tile t4 in {0,1}, lane col c in [0,16): gate g = c&3, unit jj = 2*(c>>2)+t4
//   orig Wih/Whh row = g*512 + kb*8 + jj.
// Gates i/f/g/o of one unit sit in a lane quad (shfl_xor 1/2/3 exchange);
// t4=0/1 give ADJACENT units -> one packed u32 (2xbf16) h-store per lane.

typedef float  f32x4  __attribute__((ext_vector_type(4)));
typedef __bf16 bf16x8 __attribute__((ext_vector_type(8)));
typedef __bf16 bf16;

#define HB_OFF   ((size_t)0)        // 4 x [64 x 512] bf16 = 262144 B
#define FLAG_OFF ((size_t)262144)   // 512 x u32 = 2048 B
#define ZROW_OFF ((size_t)264192)   // 512 f32 zero embedding row = 2048 B
#define WS_ZERO_BYTES ((size_t)266240)

__device__ __forceinline__ float sigmoidf_(float x) {
    return 1.0f / (1.0f + __expf(-x));
}
__device__ __forceinline__ float tanhf_(float x) {
    return 2.0f * sigmoidf_(2.0f * x) - 1.0f;
}
__device__ __forceinline__ bf16x8 cvt8(const float* p) {
    float4 a = *(const float4*)p;
    float4 b = *(const float4*)(p + 4);
    bf16x8 r;
    r[0] = (bf16)a.x; r[1] = (bf16)a.y; r[2] = (bf16)a.z; r[3] = (bf16)a.w;
    r[4] = (bf16)b.x; r[5] = (bf16)b.y; r[6] = (bf16)b.z; r[7] = (bf16)b.w;
    return r;
}

__global__ __launch_bounds__(256) void init_ws(unsigned long long* __restrict__ w) {
    const size_t i = (size_t)blockIdx.x * 256 + threadIdx.x;
    if (i < WS_ZERO_BYTES / 8) w[i] = 0ull;
}

__global__ __launch_bounds__(256, 1) void lstm_scan(
    const int*   __restrict__ data,    // [128,64] int32, -1 = pad
    const float* __restrict__ mask,    // [128,64] f32 (0/1)
    const float* __restrict__ table,   // [32001,512] f32
    const float* __restrict__ wih_f, const float* __restrict__ whh_f,
    const float* __restrict__ bih_f, const float* __restrict__ bhh_f,
    const float* __restrict__ wih_b, const float* __restrict__ whh_b,
    const float* __restrict__ bih_b, const float* __restrict__ bhh_b,
    bf16* __restrict__ hbuf,           // [dir][buf][64][512] bf16 (internal)
    unsigned* __restrict__ flags,      // 512 per-wave monotone flags
    const float* __restrict__ zrow,    // 512 zeros
    float* __restrict__ out)           // [128,64,1024] f32
{
    // Pre-swizzled weight fragments: entry e = kc*128 + t4*64 + q*16 + c
    // holds B[k = kc*32 + q*8 + j][permuted col (t4,c)] for j=0..7 (16 B).
    __shared__ bf16 sW[2048 * 8];      // Whh fragments, 32 KB
    __shared__ bf16 sV[2048 * 8];      // Wih fragments, 32 KB  (total 64 KB)

    const int tid = threadIdx.x, bid = blockIdx.x;
    const int dir = bid >> 6, kb = bid & 63;
    const int wave = tid >> 6, lane = tid & 63;
    const int c = lane & 15, q = lane >> 4, g = c & 3;

    const float* wih = dir ? wih_b : wih_f;
    const float* whh = dir ? whh_b : whh_f;
    const float* bih = dir ? bih_b : bih_f;
    const float* bhh = dir ? bhh_b : bhh_f;

    // stage weight fragments (f32 -> bf16, swizzled)
    for (int e = tid; e < 2048; e += 256) {
        const int ec = e & 15, eq = (e >> 4) & 3, et = (e >> 6) & 1, ekc = e >> 7;
        const size_t orig = (size_t)((ec & 3) * 512 + kb * 8 + 2 * (ec >> 2) + et);
        const size_t off = orig * 512 + ekc * 32 + eq * 8;
        *(bf16x8*)(&sW[e * 8]) = cvt8(&whh[off]);
        *(bf16x8*)(&sV[e * 8]) = cvt8(&wih[off]);
    }
    float bias_v[2];
#pragma unroll
    for (int t4 = 0; t4 < 2; ++t4) {
        const int orig = g * 512 + kb * 8 + 2 * (c >> 2) + t4;
        bias_v[t4] = bih[orig] + bhh[orig];
    }

    float cst[2][4] = {{0.f, 0.f, 0.f, 0.f}, {0.f, 0.f, 0.f, 0.f}};
    const int hrow = 16 * wave + c;        // A-fragment row (batch index)
    const int myflag = dir * 256 + kb * 4 + wave;
    const int fbase = dir * 256;
    const f32x4 zz = {0.f, 0.f, 0.f, 0.f};
    __syncthreads();                        // sW/sV ready; no syncs after this

    // ---- prologue: qv/mask/x-projection for step 0 (pipelined state) ----
    f32x4 accx0 = zz, accx1 = zz;
    float4 mv;
    {
        const int tt0 = dir ? 127 : 0;
        const int qv = data[tt0 * 64 + hrow];
        mv = *(const float4*)(&mask[tt0 * 64 + 16 * wave + 4 * q]);
        const float* erow = (qv >= 0) ? (table + (size_t)qv * 512) : zrow;
#pragma unroll
        for (int kc = 0; kc < 16; ++kc) {
            const bf16x8 e  = cvt8(erow + kc * 32 + q * 8);
            const bf16x8 b0 = *(const bf16x8*)(&sV[(kc * 128 + q * 16 + c) * 8]);
            const bf16x8 b1 = *(const bf16x8*)(&sV[(kc * 128 + 64 + q * 16 + c) * 8]);
            accx0 = __builtin_amdgcn_mfma_f32_16x16x32_bf16(e, b0, accx0, 0, 0, 0);
            accx1 = __builtin_amdgcn_mfma_f32_16x16x32_bf16(e, b1, accx1, 0, 0, 0);
        }
    }

    for (int s = 0; s < 128; ++s) {
        const int tt = dir ? (127 - s) : s;

        // ---- wait: all 256 waves of this dir completed step s-1 ----
        const unsigned tgt = (unsigned)s;
        for (;;) {
            const unsigned a0 = __hip_atomic_load(flags + fbase + lane,       __ATOMIC_RELAXED, __HIP_MEMORY_SCOPE_AGENT);
            const unsigned a1 = __hip_atomic_load(flags + fbase + 64  + lane, __ATOMIC_RELAXED, __HIP_MEMORY_SCOPE_AGENT);
            const unsigned a2 = __hip_atomic_load(flags + fbase + 128 + lane, __ATOMIC_RELAXED, __HIP_MEMORY_SCOPE_AGENT);
            const unsigned a3 = __hip_atomic_load(flags + fbase + 192 + lane, __ATOMIC_RELAXED, __HIP_MEMORY_SCOPE_AGENT);
            if (__all(a0 >= tgt && a1 >= tgt && a2 >= tgt && a3 >= tgt)) break;
            __builtin_amdgcn_s_sleep(1);
        }
        __asm__ volatile("" ::: "memory");   // keep h-loads below the poll

        const bf16* hb = hbuf + (size_t)(dir * 2 + (s & 1)) * (64 * 512);
        bf16*       hw = hbuf + (size_t)(dir * 2 + ((s + 1) & 1)) * (64 * 512);

        // ---- h A-fragments: ONE asm node = 16 agent-scope (sc1) dwordx4
        //      loads + s_waitcnt vmcnt(0); "=&v" keeps dests off the addr pair.
        const unsigned long long ha =
            (unsigned long long)hb + (unsigned)(hrow * 1024 + q * 16);
        uint4 af[16];
        asm volatile(
            "global_load_dwordx4 %0,  %16, off sc1\n\t"
            "global_load_dwordx4 %1,  %16, off offset:64   sc1\n\t"
            "global_load_dwordx4 %2,  %16, off offset:128  sc1\n\t"
            "global_load_dwordx4 %3,  %16, off offset:192  sc1\n\t"
            "global_load_dwordx4 %4,  %16, off offset:256  sc1\n\t"
            "global_load_dwordx4 %5,  %16, off offset:320  sc1\n\t"
            "global_load_dwordx4 %6,  %16, off offset:384  sc1\n\t"
            "global_load_dwordx4 %7,  %16, off offset:448  sc1\n\t"
            "global_load_dwordx4 %8,  %16, off offset:512  sc1\n\t"
            "global_load_dwordx4 %9,  %16, off offset:576  sc1\n\t"
            "global_load_dwordx4 %10, %16, off offset:640  sc1\n\t"
            "global_load_dwordx4 %11, %16, off offset:704  sc1\n\t"
            "global_load_dwordx4 %12, %16, off offset:768  sc1\n\t"
            "global_load_dwordx4 %13, %16, off offset:832  sc1\n\t"
            "global_load_dwordx4 %14, %16, off offset:896  sc1\n\t"
            "global_load_dwordx4 %15, %16, off offset:960  sc1\n\t"
            "s_waitcnt vmcnt(0)"
            : "=&v"(af[0]),  "=&v"(af[1]),  "=&v"(af[2]),  "=&v"(af[3]),
              "=&v"(af[4]),  "=&v"(af[5]),  "=&v"(af[6]),  "=&v"(af[7]),
              "=&v"(af[8]),  "=&v"(af[9]),  "=&v"(af[10]), "=&v"(af[11]),
              "=&v"(af[12]), "=&v"(af[13]), "=&v"(af[14]), "=&v"(af[15])
            : "v"(ha)
            : "memory");

        f32x4 acc0 = zz, acc1 = zz;
#pragma unroll
        for (int kc = 0; kc < 16; ++kc) {
            const bf16x8 a  = __builtin_bit_cast(bf16x8, af[kc]);
            const bf16x8 b0 = *(const bf16x8*)(&sW[(kc * 128 + q * 16 + c) * 8]);
            const bf16x8 b1 = *(const bf16x8*)(&sW[(kc * 128 + 64 + q * 16 + c) * 8]);
            acc0 = __builtin_amdgcn_mfma_f32_16x16x32_bf16(a, b0, acc0, 0, 0, 0);
            acc1 = __builtin_amdgcn_mfma_f32_16x16x32_bf16(a, b1, acc1, 0, 0, 0);
        }

        // ---- epilogue: C/D layout col=lane&15, row=q*4+r ----
        unsigned* hw32 = (unsigned*)hw;
        float hreg[4][2];
#pragma unroll
        for (int r = 0; r < 4; ++r) {
            const int b_ = 16 * wave + 4 * q + r;
            const float m = (&mv.x)[r];
            float hv01[2];
#pragma unroll
            for (int t4 = 0; t4 < 2; ++t4) {
                float v = (t4 ? acc1[r] : acc0[r]) + (t4 ? accx1[r] : accx0[r]) + bias_v[t4];
                const float v1 = __shfl_xor(v, 1);
                const float v2 = __shfl_xor(v, 2);
                const float v3 = __shfl_xor(v, 3);
                const float gi = (g == 0) ? v  : (g == 1) ? v1 : (g == 2) ? v2 : v3;
                const float gf = (g == 0) ? v1 : (g == 1) ? v  : (g == 2) ? v3 : v2;
                const float gG = (g == 0) ? v2 : (g == 1) ? v3 : (g == 2) ? v  : v1;
                const float go = (g == 0) ? v3 : (g == 1) ? v2 : (g == 2) ? v1 : v;
                const float cn = sigmoidf_(gf) * cst[t4][r] + sigmoidf_(gi) * tanhf_(gG);
                float hv       = sigmoidf_(go) * tanhf_(cn);
                cst[t4][r] = cn * m;       // f32 c-state never leaves registers
                hv *= m;
                hv01[t4] = hv;
            }
            hreg[r][0] = hv01[0]; hreg[r][1] = hv01[1];
            if (g == 0) {                   // packed 2xbf16 -> one u32 sc1 store
                const unsigned u =
                    (unsigned)__builtin_bit_cast(unsigned short, (bf16)hv01[0]) |
                    ((unsigned)__builtin_bit_cast(unsigned short, (bf16)hv01[1]) << 16);
                __hip_atomic_store(hw32 + b_ * 256 + kb * 4 + (c >> 2), u,
                                   __ATOMIC_RELAXED, __HIP_MEMORY_SCOPE_AGENT);
            }
        }

        // release: all h sc1-stores acked at MALL before flag store
        __asm__ volatile("" ::: "memory");
        __builtin_amdgcn_s_waitcnt(0x0F70);  // vmcnt(0)
        if (lane == 0)
            __hip_atomic_store(flags + myflag, (unsigned)(s + 1),
                               __ATOMIC_RELAXED, __HIP_MEMORY_SCOPE_AGENT);

        // ---- step tail (off the relay critical path): out-writes + next x ----
        if (g == 0) {
            const int j2 = dir * 512 + kb * 8 + 2 * (c >> 2);
#pragma unroll
            for (int r = 0; r < 4; ++r) {
                const int b_ = 16 * wave + 4 * q + r;
                float2 o2; o2.x = hreg[r][0]; o2.y = hreg[r][1];
                *(float2*)(&out[(size_t)(tt * 64 + b_) * 1024 + j2]) = o2;
            }
        }
        if (s < 127) {
            const int tt_n = dir ? (126 - s) : (s + 1);
            const int qv = data[tt_n * 64 + hrow];
            mv = *(const float4*)(&mask[tt_n * 64 + 16 * wave + 4 * q]);
            const float* erow = (qv >= 0) ? (table + (size_t)qv * 512) : zrow;
            accx0 = zz; accx1 = zz;
#pragma unroll
            for (int kc = 0; kc < 16; ++kc) {
                const bf16x8 e  = cvt8(erow + kc * 32 + q * 8);
                const bf16x8 b0 = *(const bf16x8*)(&sV[(kc * 128 + q * 16 + c) * 8]);
                const bf16x8 b1 = *(const bf16x8*)(&sV[(kc * 128 + 64 + q * 16 + c) * 8]);
                accx0 = __builtin_amdgcn_mfma_f32_16x16x32_bf16(e, b0, accx0, 0, 0, 0);
                accx1 = __builtin_amdgcn_mfma_f32_16x16x32_bf16(e, b1, accx1, 0, 0, 0);
            }
        }
    }
}

extern "C" void kernel_launch(void* const* d_in, const int* in_sizes, int n_in,
                              void* d_out, int out_size, void* d_ws, size_t ws_size,
                              hipStream_t stream) {
    const int*   data  = (const int*)d_in[0];
    const float* mask  = (const float*)d_in[1];
    const float* table = (const float*)d_in[2];
    const float* wih_f = (const float*)d_in[3];
    const float* whh_f = (const float*)d_in[4];
    const float* bih_f = (const float*)d_in[5];
    const float* bhh_f = (const float*)d_in[6];
    const float* wih_b = (const float*)d_in[7];
    const float* whh_b = (const float*)d_in[8];
    const float* bih_b = (const float*)d_in[9];
    const float* bhh_b = (const float*)d_in[10];
    float* outp = (float*)d_out;

    char* ws = (char*)d_ws;
    bf16*       hbuf  = (bf16*)(ws + HB_OFF);
    unsigned*   flagp = (unsigned*)(ws + FLAG_OFF);
    const float* zrow = (const float*)(ws + ZROW_OFF);

    init_ws<<<(int)((WS_ZERO_BYTES / 8 + 255) / 256), 256, 0, stream>>>(
        (unsigned long long*)ws);
    lstm_scan<<<128, 256, 0, stream>>>(data, mask, table,
                                       wih_f, whh_f, bih_f, bhh_f,
                                       wih_b, whh_b, bih_b, bhh_b,
                                       hbuf, flagp, zrow, outp);
}

// Round 9
// 1176.680 us; speedup vs baseline: 3.0709x; 1.3342x over previous
//
#include <hip/hip_runtime.h>

// NLReader bidirectional LSTM, MI355X — persistent scan, fence-free relay.
//
// Round-9: round-8 + x-projection latency fully decoupled. Round 8 kept the
// embedding loads and their consuming MFMAs in one loop in the step tail; at
// VGPR=124 the compiler held only ~4-8 loads in flight -> ~5 serialized MALL
// round trips per step dominated the 11.7 us/step. Now the RAW embedding data
// for step s+1 is loaded into a register array xe[32] (128 VGPR) by a pure
// load-only loop in step s's tail (after the flag post), and consumed by the
// x-MFMA at the HEAD of step s+1 (before the poll) — the loads get a full
// relay period (~2 us) to complete. Plain compiler-tracked loads: the waitcnt
// pass inserts correct (already-satisfied) waits. Token ids prefetched TWO
// steps ahead so the tail has no serial qv->emb dependency.
//
// Everything else as round 8: 128 blocks x 256 thr; cross-block h + flags via
// agent-scope (sc1, MALL) accesses, no __threadfence in the loop; h-fetch is
// ONE asm node (16x global_load_dwordx4 sc1 + s_waitcnt vmcnt(0), "=&v"
// early-clobber outputs); W-fragments pre-swizzled bf16 in LDS; f32 c-state
// in registers; h bf16 double-buffered in ws.
//
// Block (dir=bid>>6, kb=bid&63) owns 8 hidden units as 32 permuted gate cols:
//   tile t4 in {0,1}, lane col c in [0,16): gate g = c&3, unit jj = 2*(c>>2)+t4
//   orig Wih/Whh row = g*512 + kb*8 + jj.
// Gates i/f/g/o of one unit sit in a lane quad (shfl_xor 1/2/3 exchange);
// t4=0/1 give ADJACENT units -> one packed u32 (2xbf16) h-store per lane.

typedef float  f32x4  __attribute__((ext_vector_type(4)));
typedef __bf16 bf16x8 __attribute__((ext_vector_type(8)));
typedef __bf16 bf16;

#define HB_OFF   ((size_t)0)        // 4 x [64 x 512] bf16 = 262144 B
#define FLAG_OFF ((size_t)262144)   // 512 x u32 = 2048 B
#define ZROW_OFF ((size_t)264192)   // 512 f32 zero embedding row = 2048 B
#define WS_ZERO_BYTES ((size_t)266240)

__device__ __forceinline__ float sigmoidf_(float x) {
    return 1.0f / (1.0f + __expf(-x));
}
__device__ __forceinline__ float tanhf_(float x) {
    return 2.0f * sigmoidf_(2.0f * x) - 1.0f;
}
__device__ __forceinline__ bf16x8 cvt8(const float* p) {
    float4 a = *(const float4*)p;
    float4 b = *(const float4*)(p + 4);
    bf16x8 r;
    r[0] = (bf16)a.x; r[1] = (bf16)a.y; r[2] = (bf16)a.z; r[3] = (bf16)a.w;
    r[4] = (bf16)b.x; r[5] = (bf16)b.y; r[6] = (bf16)b.z; r[7] = (bf16)b.w;
    return r;
}
__device__ __forceinline__ bf16x8 cvt8v(uint4 u0, uint4 u1) {
    float4 a = __builtin_bit_cast(float4, u0);
    float4 b = __builtin_bit_cast(float4, u1);
    bf16x8 r;
    r[0] = (bf16)a.x; r[1] = (bf16)a.y; r[2] = (bf16)a.z; r[3] = (bf16)a.w;
    r[4] = (bf16)b.x; r[5] = (bf16)b.y; r[6] = (bf16)b.z; r[7] = (bf16)b.w;
    return r;
}

__global__ __launch_bounds__(256) void init_ws(unsigned long long* __restrict__ w) {
    const size_t i = (size_t)blockIdx.x * 256 + threadIdx.x;
    if (i < WS_ZERO_BYTES / 8) w[i] = 0ull;
}

__global__ __launch_bounds__(256, 1) void lstm_scan(
    const int*   __restrict__ data,    // [128,64] int32, -1 = pad
    const float* __restrict__ mask,    // [128,64] f32 (0/1)
    const float* __restrict__ table,   // [32001,512] f32
    const float* __restrict__ wih_f, const float* __restrict__ whh_f,
    const float* __restrict__ bih_f, const float* __restrict__ bhh_f,
    const float* __restrict__ wih_b, const float* __restrict__ whh_b,
    const float* __restrict__ bih_b, const float* __restrict__ bhh_b,
    bf16* __restrict__ hbuf,           // [dir][buf][64][512] bf16 (internal)
    unsigned* __restrict__ flags,      // 512 per-wave monotone flags
    const float* __restrict__ zrow,    // 512 zeros
    float* __restrict__ out)           // [128,64,1024] f32
{
    // Pre-swizzled weight fragments: entry e = kc*128 + t4*64 + q*16 + c
    // holds B[k = kc*32 + q*8 + j][permuted col (t4,c)] for j=0..7 (16 B).
    __shared__ bf16 sW[2048 * 8];      // Whh fragments, 32 KB
    __shared__ bf16 sV[2048 * 8];      // Wih fragments, 32 KB  (total 64 KB)

    const int tid = threadIdx.x, bid = blockIdx.x;
    const int dir = bid >> 6, kb = bid & 63;
    const int wave = tid >> 6, lane = tid & 63;
    const int c = lane & 15, q = lane >> 4, g = c & 3;

    const float* wih = dir ? wih_b : wih_f;
    const float* whh = dir ? whh_b : whh_f;
    const float* bih = dir ? bih_b : bih_f;
    const float* bhh = dir ? bhh_b : bhh_f;

    // stage weight fragments (f32 -> bf16, swizzled)
    for (int e = tid; e < 2048; e += 256) {
        const int ec = e & 15, eq = (e >> 4) & 3, et = (e >> 6) & 1, ekc = e >> 7;
        const size_t orig = (size_t)((ec & 3) * 512 + kb * 8 + 2 * (ec >> 2) + et);
        const size_t off = orig * 512 + ekc * 32 + eq * 8;
        *(bf16x8*)(&sW[e * 8]) = cvt8(&whh[off]);
        *(bf16x8*)(&sV[e * 8]) = cvt8(&wih[off]);
    }
    float bias_v[2];
#pragma unroll
    for (int t4 = 0; t4 < 2; ++t4) {
        const int orig = g * 512 + kb * 8 + 2 * (c >> 2) + t4;
        bias_v[t4] = bih[orig] + bhh[orig];
    }

    float cst[2][4] = {{0.f, 0.f, 0.f, 0.f}, {0.f, 0.f, 0.f, 0.f}};
    const int hrow = 16 * wave + c;        // A-fragment row (batch index)
    const int myflag = dir * 256 + kb * 4 + wave;
    const int fbase = dir * 256;
    const f32x4 zz = {0.f, 0.f, 0.f, 0.f};
    __syncthreads();                        // sW/sV ready; no syncs after this

    // ---- prologue: pipelined state for step 0 ----
    // xe[32] = raw f32 embedding row data for the CURRENT step (128 VGPR)
    // mv     = mask float4 for the current step
    // qv_n   = token id for the NEXT step (prefetched 2 steps ahead)
    uint4 xe[32];
    float4 mv;
    int qv_n;
    {
        const int tt0 = dir ? 127 : 0;
        const int qv0 = data[tt0 * 64 + hrow];
        mv = *(const float4*)(&mask[tt0 * 64 + 16 * wave + 4 * q]);
        const float* erow = (qv0 >= 0) ? (table + (size_t)qv0 * 512) : zrow;
#pragma unroll
        for (int kc = 0; kc < 16; ++kc) {
            xe[2 * kc]     = *(const uint4*)(erow + kc * 32 + q * 8);
            xe[2 * kc + 1] = *(const uint4*)(erow + kc * 32 + q * 8 + 4);
        }
        const int tt1 = dir ? 126 : 1;
        qv_n = data[tt1 * 64 + hrow];
    }

    for (int s = 0; s < 128; ++s) {
        const int tt = dir ? (127 - s) : s;

        // ---- x-projection at step HEAD: xe was loaded a full step ago ----
        f32x4 accx0 = zz, accx1 = zz;
#pragma unroll
        for (int kc = 0; kc < 16; ++kc) {
            const bf16x8 e  = cvt8v(xe[2 * kc], xe[2 * kc + 1]);
            const bf16x8 b0 = *(const bf16x8*)(&sV[(kc * 128 + q * 16 + c) * 8]);
            const bf16x8 b1 = *(const bf16x8*)(&sV[(kc * 128 + 64 + q * 16 + c) * 8]);
            accx0 = __builtin_amdgcn_mfma_f32_16x16x32_bf16(e, b0, accx0, 0, 0, 0);
            accx1 = __builtin_amdgcn_mfma_f32_16x16x32_bf16(e, b1, accx1, 0, 0, 0);
        }

        // ---- wait: all 256 waves of this dir completed step s-1 ----
        const unsigned tgt = (unsigned)s;
        for (;;) {
            const unsigned a0 = __hip_atomic_load(flags + fbase + lane,       __ATOMIC_RELAXED, __HIP_MEMORY_SCOPE_AGENT);
            const unsigned a1 = __hip_atomic_load(flags + fbase + 64  + lane, __ATOMIC_RELAXED, __HIP_MEMORY_SCOPE_AGENT);
            const unsigned a2 = __hip_atomic_load(flags + fbase + 128 + lane, __ATOMIC_RELAXED, __HIP_MEMORY_SCOPE_AGENT);
            const unsigned a3 = __hip_atomic_load(flags + fbase + 192 + lane, __ATOMIC_RELAXED, __HIP_MEMORY_SCOPE_AGENT);
            if (__all(a0 >= tgt && a1 >= tgt && a2 >= tgt && a3 >= tgt)) break;
            __builtin_amdgcn_s_sleep(1);
        }
        __asm__ volatile("" ::: "memory");   // keep h-loads below the poll

        const bf16* hb = hbuf + (size_t)(dir * 2 + (s & 1)) * (64 * 512);
        bf16*       hw = hbuf + (size_t)(dir * 2 + ((s + 1) & 1)) * (64 * 512);

        // ---- h A-fragments: ONE asm node = 16 agent-scope (sc1) dwordx4
        //      loads + s_waitcnt vmcnt(0); "=&v" keeps dests off the addr pair.
        const unsigned long long ha =
            (unsigned long long)hb + (unsigned)(hrow * 1024 + q * 16);
        uint4 af[16];
        asm volatile(
            "global_load_dwordx4 %0,  %16, off sc1\n\t"
            "global_load_dwordx4 %1,  %16, off offset:64   sc1\n\t"
            "global_load_dwordx4 %2,  %16, off offset:128  sc1\n\t"
            "global_load_dwordx4 %3,  %16, off offset:192  sc1\n\t"
            "global_load_dwordx4 %4,  %16, off offset:256  sc1\n\t"
            "global_load_dwordx4 %5,  %16, off offset:320  sc1\n\t"
            "global_load_dwordx4 %6,  %16, off offset:384  sc1\n\t"
            "global_load_dwordx4 %7,  %16, off offset:448  sc1\n\t"
            "global_load_dwordx4 %8,  %16, off offset:512  sc1\n\t"
            "global_load_dwordx4 %9,  %16, off offset:576  sc1\n\t"
            "global_load_dwordx4 %10, %16, off offset:640  sc1\n\t"
            "global_load_dwordx4 %11, %16, off offset:704  sc1\n\t"
            "global_load_dwordx4 %12, %16, off offset:768  sc1\n\t"
            "global_load_dwordx4 %13, %16, off offset:832  sc1\n\t"
            "global_load_dwordx4 %14, %16, off offset:896  sc1\n\t"
            "global_load_dwordx4 %15, %16, off offset:960  sc1\n\t"
            "s_waitcnt vmcnt(0)"
            : "=&v"(af[0]),  "=&v"(af[1]),  "=&v"(af[2]),  "=&v"(af[3]),
              "=&v"(af[4]),  "=&v"(af[5]),  "=&v"(af[6]),  "=&v"(af[7]),
              "=&v"(af[8]),  "=&v"(af[9]),  "=&v"(af[10]), "=&v"(af[11]),
              "=&v"(af[12]), "=&v"(af[13]), "=&v"(af[14]), "=&v"(af[15])
            : "v"(ha)
            : "memory");

        f32x4 acc0 = zz, acc1 = zz;
#pragma unroll
        for (int kc = 0; kc < 16; ++kc) {
            const bf16x8 a  = __builtin_bit_cast(bf16x8, af[kc]);
            const bf16x8 b0 = *(const bf16x8*)(&sW[(kc * 128 + q * 16 + c) * 8]);
            const bf16x8 b1 = *(const bf16x8*)(&sW[(kc * 128 + 64 + q * 16 + c) * 8]);
            acc0 = __builtin_amdgcn_mfma_f32_16x16x32_bf16(a, b0, acc0, 0, 0, 0);
            acc1 = __builtin_amdgcn_mfma_f32_16x16x32_bf16(a, b1, acc1, 0, 0, 0);
        }

        // ---- epilogue: C/D layout col=lane&15, row=q*4+r ----
        unsigned* hw32 = (unsigned*)hw;
        float hreg[4][2];
#pragma unroll
        for (int r = 0; r < 4; ++r) {
            const int b_ = 16 * wave + 4 * q + r;
            const float m = (&mv.x)[r];
            float hv01[2];
#pragma unroll
            for (int t4 = 0; t4 < 2; ++t4) {
                float v = (t4 ? acc1[r] : acc0[r]) + (t4 ? accx1[r] : accx0[r]) + bias_v[t4];
                const float v1 = __shfl_xor(v, 1);
                const float v2 = __shfl_xor(v, 2);
                const float v3 = __shfl_xor(v, 3);
                const float gi = (g == 0) ? v  : (g == 1) ? v1 : (g == 2) ? v2 : v3;
                const float gf = (g == 0) ? v1 : (g == 1) ? v  : (g == 2) ? v3 : v2;
                const float gG = (g == 0) ? v2 : (g == 1) ? v3 : (g == 2) ? v  : v1;
                const float go = (g == 0) ? v3 : (g == 1) ? v2 : (g == 2) ? v1 : v;
                const float cn = sigmoidf_(gf) * cst[t4][r] + sigmoidf_(gi) * tanhf_(gG);
                float hv       = sigmoidf_(go) * tanhf_(cn);
                cst[t4][r] = cn * m;       // f32 c-state never leaves registers
                hv *= m;
                hv01[t4] = hv;
            }
            hreg[r][0] = hv01[0]; hreg[r][1] = hv01[1];
            if (g == 0) {                   // packed 2xbf16 -> one u32 sc1 store
                const unsigned u =
                    (unsigned)__builtin_bit_cast(unsigned short, (bf16)hv01[0]) |
                    ((unsigned)__builtin_bit_cast(unsigned short, (bf16)hv01[1]) << 16);
                __hip_atomic_store(hw32 + b_ * 256 + kb * 4 + (c >> 2), u,
                                   __ATOMIC_RELAXED, __HIP_MEMORY_SCOPE_AGENT);
            }
        }

        // release: all h sc1-stores acked at MALL before flag store
        __asm__ volatile("" ::: "memory");
        __builtin_amdgcn_s_waitcnt(0x0F70);  // vmcnt(0)
        if (lane == 0)
            __hip_atomic_store(flags + myflag, (unsigned)(s + 1),
                               __ATOMIC_RELAXED, __HIP_MEMORY_SCOPE_AGENT);

        // ---- step tail (hidden behind other blocks' consumption) ----
        // out-writes, then pure load-only prefetch of next step's embeddings
        // into xe (no dependent compute -> all 32 loads go out back-to-back
        // and have the whole relay period to land).
        if (g == 0) {
            const int j2 = dir * 512 + kb * 8 + 2 * (c >> 2);
#pragma unroll
            for (int r = 0; r < 4; ++r) {
                const int b_ = 16 * wave + 4 * q + r;
                float2 o2; o2.x = hreg[r][0]; o2.y = hreg[r][1];
                *(float2*)(&out[(size_t)(tt * 64 + b_) * 1024 + j2]) = o2;
            }
        }
        if (s < 127) {
            const int tt_n = dir ? (126 - s) : (s + 1);
            const float* erow = (qv_n >= 0) ? (table + (size_t)qv_n * 512) : zrow;
#pragma unroll
            for (int kc = 0; kc < 16; ++kc) {
                xe[2 * kc]     = *(const uint4*)(erow + kc * 32 + q * 8);
                xe[2 * kc + 1] = *(const uint4*)(erow + kc * 32 + q * 8 + 4);
            }
            mv = *(const float4*)(&mask[tt_n * 64 + 16 * wave + 4 * q]);
            if (s < 126) {
                const int tt_n2 = dir ? (125 - s) : (s + 2);
                qv_n = data[tt_n2 * 64 + hrow];
            }
        }
    }
}

extern "C" void kernel_launch(void* const* d_in, const int* in_sizes, int n_in,
                              void* d_out, int out_size, void* d_ws, size_t ws_size,
                              hipStream_t stream) {
    const int*   data  = (const int*)d_in[0];
    const float* mask  = (const float*)d_in[1];
    const float* table = (const float*)d_in[2];
    const float* wih_f = (const float*)d_in[3];
    const float* whh_f = (const float*)d_in[4];
    const float* bih_f = (const float*)d_in[5];
    const float* bhh_f = (const float*)d_in[6];
    const float* wih_b = (const float*)d_in[7];
    const float* whh_b = (const float*)d_in[8];
    const float* bih_b = (const float*)d_in[9];
    const float* bhh_b = (const float*)d_in[10];
    float* outp = (float*)d_out;

    char* ws = (char*)d_ws;
    bf16*       hbuf  = (bf16*)(ws + HB_OFF);
    unsigned*   flagp = (unsigned*)(ws + FLAG_OFF);
    const float* zrow = (const float*)(ws + ZROW_OFF);

    init_ws<<<(int)((WS_ZERO_BYTES / 8 + 255) / 256), 256, 0, stream>>>(
        (unsigned long long*)ws);
    lstm_scan<<<128, 256, 0, stream>>>(data, mask, table,
                                       wih_f, whh_f, bih_f, bhh_f,
                                       wih_b, whh_b, bih_b, bhh_b,
                                       hbuf, flagp, zrow, outp);
}